// Round 8
// baseline (110.407 us; speedup 1.0000x reference)
//
#include <hip/hip_runtime.h>
#include <hip/hip_bf16.h>

#define QLEN   1024
#define MLEN   1024
#define KLEN   2048
#define BATCH  8
#define DMODEL 1024
#define NCOLS  (BATCH * DMODEL)   // 8192
#define FTLEN  1025

#define BM 128
#define BN 256
#define BK 64
#define NT 18   // band: K in [m0, m0+1152), 18 tiles of 64

typedef __attribute__((ext_vector_type(4))) float f32x4;
typedef __attribute__((ext_vector_type(8))) short bf16x8;

typedef __attribute__((address_space(1))) const unsigned int as1_u32;
typedef __attribute__((address_space(3))) unsigned int as3_u32;

static __device__ __forceinline__ unsigned short f2bf(float f) {
    unsigned int u = __builtin_bit_cast(unsigned int, f);
    return (unsigned short)((u + 0x7fffu + ((u >> 16) & 1u)) >> 16);
}
static __device__ __forceinline__ float bf2f(unsigned short s) {
    return __builtin_bit_cast(float, (unsigned int)s << 16);
}
static __device__ __forceinline__ unsigned int packbf(float lo, float hi) {
    return (unsigned int)f2bf(lo) | ((unsigned int)f2bf(hi) << 16);
}

// ---------------------------------------------------------------------------
// Kernel 1: cat = concat(mems, dec) (+ pos_emb), cast bf16, store TRANSPOSED
// catT[n][k] (n = b*1024+d, k = l contiguous). Pair-packed u32 LDS transpose.
// ---------------------------------------------------------------------------
__global__ __launch_bounds__(256) void prep_transpose2(
    const float* __restrict__ dec, const float* __restrict__ pos,
    const float* __restrict__ mems, const int* __restrict__ addp,
    unsigned short* __restrict__ catT)
{
    __shared__ unsigned int T2[32 * 68];   // 8704 B, stride 68 u32
    const int tid = threadIdx.x;
    const int lt = blockIdx.x, dt = blockIdx.y, b = blockIdx.z;
    const int l0 = lt * 64, d0 = dt * 64;
    const int add_position = addp[0];

    const int dloc  = (tid & 15) * 4;   // 0..60
    const int lhalf = tid >> 4;         // 0..15

    float4 vc[2][2];
#pragma unroll
    for (int p = 0; p < 2; ++p)
#pragma unroll
        for (int jl = 0; jl < 2; ++jl) {
            const int l = l0 + p * 32 + lhalf * 2 + jl;
            const float* src = (l < MLEN)
                ? (mems + (size_t)l * NCOLS + b * DMODEL + d0 + dloc)
                : (dec + (size_t)(l - MLEN) * NCOLS + b * DMODEL + d0 + dloc);
            vc[p][jl] = *reinterpret_cast<const float4*>(src);
        }
    if (add_position) {
#pragma unroll
        for (int p = 0; p < 2; ++p)
#pragma unroll
            for (int jl = 0; jl < 2; ++jl) {
                const int l = l0 + p * 32 + lhalf * 2 + jl;
                float4 pv = *reinterpret_cast<const float4*>(
                    pos + (size_t)l * DMODEL + d0 + dloc);
                vc[p][jl].x += pv.x; vc[p][jl].y += pv.y;
                vc[p][jl].z += pv.z; vc[p][jl].w += pv.w;
            }
    }
#pragma unroll
    for (int p = 0; p < 2; ++p) {
        const int lp = p * 16 + lhalf;   // 0..31
        uint4 w;
        w.x = packbf(vc[p][0].x, vc[p][1].x);
        w.y = packbf(vc[p][0].y, vc[p][1].y);
        w.z = packbf(vc[p][0].z, vc[p][1].z);
        w.w = packbf(vc[p][0].w, vc[p][1].w);
        *reinterpret_cast<uint4*>(&T2[lp * 68 + dloc]) = w;
    }
    __syncthreads();
    const int d = tid >> 2;              // 0..63
    const size_t n = (size_t)b * DMODEL + d0 + d;
#pragma unroll
    for (int q = 0; q < 2; ++q) {
        const int c8 = (tid & 3) + 4 * q;    // 0..7
        uint4 o;
        o.x = T2[(c8 * 4 + 0) * 68 + d];
        o.y = T2[(c8 * 4 + 1) * 68 + d];
        o.z = T2[(c8 * 4 + 2) * 68 + d];
        o.w = T2[(c8 * 4 + 3) * 68 + d];
        *reinterpret_cast<uint4*>(&catT[n * KLEN + l0 + c8 * 8]) = o;
    }
}

// ---------------------------------------------------------------------------
// Kernel 2: W[m][k] bf16, W[m][m+t] = cos(2*pi*(m*t mod 1025)/1025)/sqrt(1025)
// ---------------------------------------------------------------------------
__global__ __launch_bounds__(256) void fill_w(unsigned short* __restrict__ W)
{
    const int idx = blockIdx.x * 256 + threadIdx.x;
    const int m = idx >> 9;
    const int k4 = (idx & 511) * 4;
    union { unsigned short s[4]; int2 v; } u;
    for (int j = 0; j < 4; ++j) {
        const int k = k4 + j;
        const int t = k - m;
        float w = 0.0f;
        if (t >= 0 && t < FTLEN) {
            const int r = (m * t) % FTLEN;
            const float x = (float)r * (1.0f / (float)FTLEN);  // revolutions
            float c;
            asm("v_cos_f32 %0, %1" : "=v"(c) : "v"(x));
            w = c * 0.03123475237772121f;   // 1/sqrt(1025)
        }
        u.s[j] = f2bf(w);
    }
    *reinterpret_cast<int2*>(&W[(size_t)m * KLEN + k4]) = u.v;
}

// ---------------------------------------------------------------------------
// Kernel 3: banded GEMM (identical to R5's gemm_band4 — best-known config).
// ATTRIBUTION ROUND: launched 3x; Delta(total)/2 = warm gemm duration.
// ---------------------------------------------------------------------------
__global__ __launch_bounds__(512) void gemm_band4(
    const unsigned short* __restrict__ W,     // [1024][2048]
    const unsigned short* __restrict__ catT,  // [8192][2048]
    unsigned short* __restrict__ ftout)       // bf16 [1024][8192]
{
    __shared__ unsigned short Alds[3][BM * BK];   // 3 x 16KB
    __shared__ unsigned short Blds[3][BN * BK];   // 3 x 32KB  (total 144KB)

    const int tid = threadIdx.x;
    const int wave = tid >> 6, lane = tid & 63;

    const int bid = blockIdx.x;
    const int xcd = bid & 7;
    const int kk = bid >> 3;              // 0..31
    const int m_idx = kk >> 2;            // 0..7
    const int n_idx = xcd * 4 + (kk & 3); // 0..31
    const int m0 = m_idx * BM, n0 = n_idx * BN;
    const int wm = wave >> 2, wn = wave & 3;   // 2 x 4 wave grid

    f32x4 acc[4][4];
    for (int i = 0; i < 4; ++i)
        for (int j = 0; j < 4; ++j)
            acc[i][j] = (f32x4){0.f, 0.f, 0.f, 0.f};

    const int srow = tid >> 3;           // 0..63
    const int scol = (((tid & 7) ^ ((tid >> 3) & 7)) * 8);
    const int fr = lane & 15;
    const int kg = lane >> 4;
    const int rswz = (fr & 7) * 8;       // read-side XOR (elements)

#define STAGE_LOAD_A(S, T, P) do {                                              \
    const int k0_ = m0 + (T) * BK;                                              \
    const int row = (P) * 64 + srow;                                            \
    __builtin_amdgcn_global_load_lds(                                           \
        (as1_u32*)(const void*)(W + (size_t)(m0 + row) * KLEN + k0_ + scol),    \
        (as3_u32*)(void*)(&Alds[S][row * BK + scol]), 16, 0, 0);                \
} while (0)
#define STAGE_LOAD_B(S, T, P) do {                                              \
    const int k0_ = m0 + (T) * BK;                                              \
    const int row = (P) * 64 + srow;                                            \
    __builtin_amdgcn_global_load_lds(                                           \
        (as1_u32*)(const void*)(catT + (size_t)(n0 + row) * KLEN + k0_ + scol), \
        (as3_u32*)(void*)(&Blds[S][row * BK + scol]), 16, 0, 0);                \
} while (0)
#define STAGE_ALL(S, T) do {                                                    \
    STAGE_LOAD_A(S, T, 0); STAGE_LOAD_A(S, T, 1);                               \
    STAGE_LOAD_B(S, T, 0); STAGE_LOAD_B(S, T, 1);                               \
    STAGE_LOAD_B(S, T, 2); STAGE_LOAD_B(S, T, 3);                               \
} while (0)

    STAGE_ALL(0, 0);
    STAGE_ALL(1, 1);

    for (int t = 0; t < NT; ++t) {
        if (t == NT - 1)
            asm volatile("s_waitcnt vmcnt(0)" ::: "memory");
        else
            asm volatile("s_waitcnt vmcnt(6)" ::: "memory");
        __builtin_amdgcn_s_barrier();

        const unsigned short* Ab = Alds[t % 3];
        const unsigned short* Bb = Blds[t % 3];
        const int s2 = (t + 2) % 3;
        const bool pf = (t + 2 < NT);

        // ---------------- phase 0 (ks = 0) ----------------
        {
            bf16x8 a[4], b[4];
#pragma unroll
            for (int f = 0; f < 4; ++f)
                a[f] = *reinterpret_cast<const bf16x8*>(
                    Ab + (wm * 64 + f * 16 + fr) * BK + ((kg * 8) ^ rswz));
#pragma unroll
            for (int f = 0; f < 4; ++f)
                b[f] = *reinterpret_cast<const bf16x8*>(
                    Bb + (wn * 64 + f * 16 + fr) * BK + ((kg * 8) ^ rswz));
            if (pf) { STAGE_LOAD_A(s2, t + 2, 0); STAGE_LOAD_B(s2, t + 2, 0); STAGE_LOAD_B(s2, t + 2, 1); }
            __builtin_amdgcn_s_barrier();
            asm volatile("s_waitcnt lgkmcnt(0)" ::: "memory");
            __builtin_amdgcn_s_setprio(1);
#pragma unroll
            for (int fm = 0; fm < 4; ++fm)
#pragma unroll
                for (int fn = 0; fn < 4; ++fn)
                    acc[fm][fn] = __builtin_amdgcn_mfma_f32_16x16x32_bf16(
                        a[fm], b[fn], acc[fm][fn], 0, 0, 0);
            __builtin_amdgcn_s_setprio(0);
            __builtin_amdgcn_s_barrier();
        }
        // ---------------- phase 1 (ks = 1) ----------------
        {
            bf16x8 a[4], b[4];
#pragma unroll
            for (int f = 0; f < 4; ++f)
                a[f] = *reinterpret_cast<const bf16x8*>(
                    Ab + (wm * 64 + f * 16 + fr) * BK + ((32 + kg * 8) ^ rswz));
#pragma unroll
            for (int f = 0; f < 4; ++f)
                b[f] = *reinterpret_cast<const bf16x8*>(
                    Bb + (wn * 64 + f * 16 + fr) * BK + ((32 + kg * 8) ^ rswz));
            if (pf) { STAGE_LOAD_A(s2, t + 2, 1); STAGE_LOAD_B(s2, t + 2, 2); STAGE_LOAD_B(s2, t + 2, 3); }
            __builtin_amdgcn_s_barrier();
            asm volatile("s_waitcnt lgkmcnt(0)" ::: "memory");
            __builtin_amdgcn_s_setprio(1);
#pragma unroll
            for (int fm = 0; fm < 4; ++fm)
#pragma unroll
                for (int fn = 0; fn < 4; ++fn)
                    acc[fm][fn] = __builtin_amdgcn_mfma_f32_16x16x32_bf16(
                        a[fm], b[fn], acc[fm][fn], 0, 0, 0);
            __builtin_amdgcn_s_setprio(0);
        }
    }
#undef STAGE_ALL
#undef STAGE_LOAD_A
#undef STAGE_LOAD_B

    const int col16 = lane & 15, rquad = lane >> 4;
#pragma unroll
    for (int fm = 0; fm < 4; ++fm)
#pragma unroll
        for (int fn = 0; fn < 4; ++fn)
#pragma unroll
            for (int j = 0; j < 4; ++j) {
                const int m = m0 + wm * 64 + fm * 16 + rquad * 4 + j;
                const int n = n0 + wn * 64 + fn * 16 + col16;
                ftout[(size_t)m * NCOLS + n] = f2bf(acc[fm][fn][j]);
            }
}

// ---------------------------------------------------------------------------
// Kernel 4: out = LayerNorm(dec + ft/sqrt(2048)) over d=1024 per (m,b) row.
// ---------------------------------------------------------------------------
__global__ __launch_bounds__(256) void layernorm_rows(
    const unsigned short* __restrict__ ft, const float* __restrict__ dec,
    const float* __restrict__ gamma, const float* __restrict__ beta,
    float* __restrict__ out)
{
    __shared__ float ps[4], pq[4];
    const int row = blockIdx.x;
    const int tid = threadIdx.x;
    const float inv = 0.022097086912079612f;  // 1/sqrt(2048)
    const size_t base = (size_t)row * DMODEL + tid * 4;
    ushort4 u = *reinterpret_cast<const ushort4*>(ft + base);
    float4 dv = *reinterpret_cast<const float4*>(dec + base);
    float vx = dv.x + bf2f(u.x) * inv;
    float vy = dv.y + bf2f(u.y) * inv;
    float vz = dv.z + bf2f(u.z) * inv;
    float vw = dv.w + bf2f(u.w) * inv;
    float s  = vx + vy + vz + vw;
    float sq = vx * vx + vy * vy + vz * vz + vw * vw;
    for (int off = 32; off > 0; off >>= 1) {
        s  += __shfl_down(s, off);
        sq += __shfl_down(sq, off);
    }
    const int wave = tid >> 6, lane = tid & 63;
    if (lane == 0) { ps[wave] = s; pq[wave] = sq; }
    __syncthreads();
    if (tid == 0) {
        float ts = ps[0] + ps[1] + ps[2] + ps[3];
        float tq = pq[0] + pq[1] + pq[2] + pq[3];
        float mu = ts * (1.0f / DMODEL);
        float var = tq * (1.0f / DMODEL) - mu * mu;
        ps[0] = mu;
        pq[0] = rsqrtf(var + 1e-5f);
    }
    __syncthreads();
    const float mu = ps[0], rs = pq[0];
    float4 g  = *reinterpret_cast<const float4*>(gamma + tid * 4);
    float4 be = *reinterpret_cast<const float4*>(beta + tid * 4);
    float4 o;
    o.x = g.x * (vx - mu) * rs + be.x;
    o.y = g.y * (vy - mu) * rs + be.y;
    o.z = g.z * (vz - mu) * rs + be.z;
    o.w = g.w * (vw - mu) * rs + be.w;
    *reinterpret_cast<float4*>(out + base) = o;
}

extern "C" void kernel_launch(void* const* d_in, const int* in_sizes, int n_in,
                              void* d_out, int out_size, void* d_ws, size_t ws_size,
                              hipStream_t stream)
{
    const float* dec   = (const float*)d_in[0];
    const float* pos   = (const float*)d_in[1];
    const float* mems  = (const float*)d_in[2];
    const float* gamma = (const float*)d_in[3];
    const float* beta  = (const float*)d_in[4];
    const int*   addp  = (const int*)d_in[5];
    float* out = (float*)d_out;

    // ws: catT bf16 [8192][2048] (32MB) | W bf16 [1024][2048] (4MB) | ft bf16 (16MB)
    unsigned short* catT = (unsigned short*)d_ws;
    unsigned short* Wmat = catT + (size_t)NCOLS * KLEN;
    unsigned short* ft   = Wmat + (size_t)QLEN * KLEN;

    prep_transpose2<<<dim3(32, 16, 8), 256, 0, stream>>>(dec, pos, mems, addp, catT);
    fill_w<<<2048, 256, 0, stream>>>(Wmat);
    // ATTRIBUTION: gemm launched 3x (idempotent). gemm_warm = (total - 64.1)/2.
    gemm_band4<<<256, 512, 0, stream>>>(Wmat, catT, ft);
    gemm_band4<<<256, 512, 0, stream>>>(Wmat, catT, ft);
    gemm_band4<<<256, 512, 0, stream>>>(Wmat, catT, ft);
    layernorm_rows<<<8192, 256, 0, stream>>>(ft, dec, gamma, beta, out);
}

// Round 9
// 87.315 us; speedup vs baseline: 1.2645x; 1.2645x over previous
//
#include <hip/hip_runtime.h>
#include <hip/hip_bf16.h>

#define QLEN   1024
#define MLEN   1024
#define KLEN   2048
#define BATCH  8
#define DMODEL 1024
#define NCOLS  (BATCH * DMODEL)   // 8192
#define FTLEN  1025

#define BM 128
#define BN 256
#define BK 64
#define NT 18   // band: K in [m0, m0+1152), 18 tiles of 64

typedef __attribute__((ext_vector_type(4))) float f32x4;
typedef __attribute__((ext_vector_type(8))) short bf16x8;

typedef __attribute__((address_space(1))) const unsigned int as1_u32;
typedef __attribute__((address_space(3))) unsigned int as3_u32;

static __device__ __forceinline__ unsigned short f2bf(float f) {
    unsigned int u = __builtin_bit_cast(unsigned int, f);
    return (unsigned short)((u + 0x7fffu + ((u >> 16) & 1u)) >> 16);
}
static __device__ __forceinline__ float bf2f(unsigned short s) {
    return __builtin_bit_cast(float, (unsigned int)s << 16);
}
static __device__ __forceinline__ unsigned int packbf(float lo, float hi) {
    return (unsigned int)f2bf(lo) | ((unsigned int)f2bf(hi) << 16);
}

// ---------------------------------------------------------------------------
// Kernel 1: cat = concat(mems, dec) (+ pos_emb), cast bf16, store TRANSPOSED
// catT[n][k] (n = b*1024+d, k = l contiguous). Pair-packed u32 LDS transpose.
// ---------------------------------------------------------------------------
__global__ __launch_bounds__(256) void prep_transpose2(
    const float* __restrict__ dec, const float* __restrict__ pos,
    const float* __restrict__ mems, const int* __restrict__ addp,
    unsigned short* __restrict__ catT)
{
    __shared__ unsigned int T2[32 * 68];   // 8704 B, stride 68 u32
    const int tid = threadIdx.x;
    const int lt = blockIdx.x, dt = blockIdx.y, b = blockIdx.z;
    const int l0 = lt * 64, d0 = dt * 64;
    const int add_position = addp[0];

    const int dloc  = (tid & 15) * 4;   // 0..60
    const int lhalf = tid >> 4;         // 0..15

    float4 vc[2][2];
#pragma unroll
    for (int p = 0; p < 2; ++p)
#pragma unroll
        for (int jl = 0; jl < 2; ++jl) {
            const int l = l0 + p * 32 + lhalf * 2 + jl;
            const float* src = (l < MLEN)
                ? (mems + (size_t)l * NCOLS + b * DMODEL + d0 + dloc)
                : (dec + (size_t)(l - MLEN) * NCOLS + b * DMODEL + d0 + dloc);
            vc[p][jl] = *reinterpret_cast<const float4*>(src);
        }
    if (add_position) {
#pragma unroll
        for (int p = 0; p < 2; ++p)
#pragma unroll
            for (int jl = 0; jl < 2; ++jl) {
                const int l = l0 + p * 32 + lhalf * 2 + jl;
                float4 pv = *reinterpret_cast<const float4*>(
                    pos + (size_t)l * DMODEL + d0 + dloc);
                vc[p][jl].x += pv.x; vc[p][jl].y += pv.y;
                vc[p][jl].z += pv.z; vc[p][jl].w += pv.w;
            }
    }
#pragma unroll
    for (int p = 0; p < 2; ++p) {
        const int lp = p * 16 + lhalf;   // 0..31
        uint4 w;
        w.x = packbf(vc[p][0].x, vc[p][1].x);
        w.y = packbf(vc[p][0].y, vc[p][1].y);
        w.z = packbf(vc[p][0].z, vc[p][1].z);
        w.w = packbf(vc[p][0].w, vc[p][1].w);
        *reinterpret_cast<uint4*>(&T2[lp * 68 + dloc]) = w;
    }
    __syncthreads();
    const int d = tid >> 2;              // 0..63
    const size_t n = (size_t)b * DMODEL + d0 + d;
#pragma unroll
    for (int q = 0; q < 2; ++q) {
        const int c8 = (tid & 3) + 4 * q;    // 0..7
        uint4 o;
        o.x = T2[(c8 * 4 + 0) * 68 + d];
        o.y = T2[(c8 * 4 + 1) * 68 + d];
        o.z = T2[(c8 * 4 + 2) * 68 + d];
        o.w = T2[(c8 * 4 + 3) * 68 + d];
        *reinterpret_cast<uint4*>(&catT[n * KLEN + l0 + c8 * 8]) = o;
    }
}

// ---------------------------------------------------------------------------
// Kernel 2: W[m][k] bf16, W[m][m+t] = cos(2*pi*(m*t mod 1025)/1025)/sqrt(1025)
// ---------------------------------------------------------------------------
__global__ __launch_bounds__(256) void fill_w(unsigned short* __restrict__ W)
{
    const int idx = blockIdx.x * 256 + threadIdx.x;
    const int m = idx >> 9;
    const int k4 = (idx & 511) * 4;
    union { unsigned short s[4]; int2 v; } u;
    for (int j = 0; j < 4; ++j) {
        const int k = k4 + j;
        const int t = k - m;
        float w = 0.0f;
        if (t >= 0 && t < FTLEN) {
            const int r = (m * t) % FTLEN;
            const float x = (float)r * (1.0f / (float)FTLEN);  // revolutions
            float c;
            asm("v_cos_f32 %0, %1" : "=v"(c) : "v"(x));
            w = c * 0.03123475237772121f;   // 1/sqrt(1025)
        }
        u.s[j] = f2bf(w);
    }
    *reinterpret_cast<int2*>(&W[(size_t)m * KLEN + k4]) = u.v;
}

// ---------------------------------------------------------------------------
// Kernel 3: banded GEMM v8 — A-operand in REGISTERS (direct global loads of
// W fragments, double-buffered reg sets), B-only LDS (3 x 32KB, XOR-swizzled,
// global_load_lds staged). Counted-vmcnt: loop-top vmcnt(12) retires B(t);
// pre-MFMA vmcnt(8) retires A(t). LDS read traffic per K-tile halves
// (512 -> 256 clk/CU) vs 308 clk MFMA -> MFMA-bound.
// ---------------------------------------------------------------------------
__global__ __launch_bounds__(512) void gemm_band8(
    const unsigned short* __restrict__ W,     // [1024][2048]
    const unsigned short* __restrict__ catT,  // [8192][2048]
    unsigned short* __restrict__ ftout)       // bf16 [1024][8192]
{
    __shared__ unsigned short Blds[3][BN * BK];   // 3 x 32KB = 96KB

    const int tid = threadIdx.x;
    const int wave = tid >> 6, lane = tid & 63;

    const int bid = blockIdx.x;
    const int xcd = bid & 7;
    const int kk = bid >> 3;              // 0..31
    const int m_idx = kk >> 2;            // 0..7
    const int n_idx = xcd * 4 + (kk & 3); // 0..31
    const int m0 = m_idx * BM, n0 = n_idx * BN;
    const int wm = wave >> 2, wn = wave & 3;   // 2m x 4n wave grid

    f32x4 acc[4][4];
    for (int i = 0; i < 4; ++i)
        for (int j = 0; j < 4; ++j)
            acc[i][j] = (f32x4){0.f, 0.f, 0.f, 0.f};

    const int srow = tid >> 3;           // 0..63
    const int scol = (((tid & 7) ^ ((tid >> 3) & 7)) * 8);  // pre-swizzled src col
    const int fr = lane & 15;
    const int kg = lane >> 4;
    const int rswz = (fr & 7) * 8;       // read-side XOR (elements)

    // Per-lane A-fragment pointers, f = 0..3; start at k0(t=0) = m0.
    // a[ks][f] elem j = W[wm*64+f*16+fr + m0][k0 + ks*32 + kg*8 + j]
    const unsigned short* pA0 = W + (size_t)(m0 + wm * 64 + 0 * 16 + fr) * KLEN + m0 + kg * 8;
    const unsigned short* pA1 = W + (size_t)(m0 + wm * 64 + 1 * 16 + fr) * KLEN + m0 + kg * 8;
    const unsigned short* pA2 = W + (size_t)(m0 + wm * 64 + 2 * 16 + fr) * KLEN + m0 + kg * 8;
    const unsigned short* pA3 = W + (size_t)(m0 + wm * 64 + 3 * 16 + fr) * KLEN + m0 + kg * 8;

    bf16x8 aA[2][4], aB[2][4];   // (ks, f) — two tile-buffers, static-indexed

#define LOAD_A_KS(AN, KS) do {                                                  \
    AN[KS][0] = *reinterpret_cast<const bf16x8*>(pA0 + (KS) * 32);              \
    AN[KS][1] = *reinterpret_cast<const bf16x8*>(pA1 + (KS) * 32);              \
    AN[KS][2] = *reinterpret_cast<const bf16x8*>(pA2 + (KS) * 32);              \
    AN[KS][3] = *reinterpret_cast<const bf16x8*>(pA3 + (KS) * 32);              \
} while (0)
#define ADV_A() do { pA0 += BK; pA1 += BK; pA2 += BK; pA3 += BK; } while (0)

#define STAGE_B(S, T, P) do {                                                   \
    const int k0_ = m0 + (T) * BK;                                              \
    const int row = (P) * 64 + srow;                                            \
    __builtin_amdgcn_global_load_lds(                                           \
        (as1_u32*)(const void*)(catT + (size_t)(n0 + row) * KLEN + k0_ + scol), \
        (as3_u32*)(void*)(&Blds[S][row * BK + scol]), 16, 0, 0);                \
} while (0)

    // prologue — emulates steady-state issue order (age-exact for the waits):
    // B(0)x4 | A(0)ks0 x4 | B(1)x2 | A(0)ks1 x4 | B(1)x2
    STAGE_B(0, 0, 0); STAGE_B(0, 0, 1); STAGE_B(0, 0, 2); STAGE_B(0, 0, 3);
    LOAD_A_KS(aA, 0);
    STAGE_B(1, 1, 0); STAGE_B(1, 1, 1);
    LOAD_A_KS(aA, 1);
    STAGE_B(1, 1, 2); STAGE_B(1, 1, 3);
    ADV_A();   // pA now at tile 1

#define ITER(T, AC, AN) do {                                                    \
    /* retire own B(T) staging, then make it LDS-visible */                     \
    if ((T) == NT - 1) asm volatile("s_waitcnt vmcnt(8)" ::: "memory");         \
    else               asm volatile("s_waitcnt vmcnt(12)" ::: "memory");        \
    __builtin_amdgcn_s_barrier();                                               \
    const unsigned short* Bb = Blds[(T) % 3];                                   \
    const int s2_ = ((T) + 2) % 3;                                              \
    const bool pfA = (T) + 1 < NT, pfB = (T) + 2 < NT;                          \
    /* ---- phase 0 (ks=0) ---- */                                              \
    {                                                                           \
        bf16x8 b[4];                                                            \
        _Pragma("unroll")                                                       \
        for (int f = 0; f < 4; ++f)                                             \
            b[f] = *reinterpret_cast<const bf16x8*>(                            \
                Bb + (wn * 64 + f * 16 + fr) * BK + ((kg * 8) ^ rswz));         \
        if (pfA) LOAD_A_KS(AN, 0);                                              \
        if (pfB) { STAGE_B(s2_, (T) + 2, 0); STAGE_B(s2_, (T) + 2, 1); }        \
        __builtin_amdgcn_s_barrier();                                           \
        if ((T) == NT - 1)                                                      \
            asm volatile("s_waitcnt vmcnt(0) lgkmcnt(0)" ::: "memory");         \
        else if ((T) == NT - 2)                                                 \
            asm volatile("s_waitcnt vmcnt(6) lgkmcnt(0)" ::: "memory");         \
        else                                                                    \
            asm volatile("s_waitcnt vmcnt(8) lgkmcnt(0)" ::: "memory");         \
        __builtin_amdgcn_s_setprio(1);                                          \
        _Pragma("unroll")                                                       \
        for (int fm = 0; fm < 4; ++fm)                                          \
            _Pragma("unroll")                                                   \
            for (int fn = 0; fn < 4; ++fn)                                      \
                acc[fm][fn] = __builtin_amdgcn_mfma_f32_16x16x32_bf16(          \
                    AC[0][fm], b[fn], acc[fm][fn], 0, 0, 0);                    \
        __builtin_amdgcn_s_setprio(0);                                          \
        __builtin_amdgcn_s_barrier();                                           \
    }                                                                           \
    /* ---- phase 1 (ks=1) ---- */                                              \
    {                                                                           \
        bf16x8 b[4];                                                            \
        _Pragma("unroll")                                                       \
        for (int f = 0; f < 4; ++f)                                             \
            b[f] = *reinterpret_cast<const bf16x8*>(                            \
                Bb + (wn * 64 + f * 16 + fr) * BK + ((32 + kg * 8) ^ rswz));    \
        if (pfA) LOAD_A_KS(AN, 1);                                              \
        if (pfB) { STAGE_B(s2_, (T) + 2, 2); STAGE_B(s2_, (T) + 2, 3); }        \
        __builtin_amdgcn_s_barrier();                                           \
        asm volatile("s_waitcnt lgkmcnt(0)" ::: "memory");                      \
        __builtin_amdgcn_s_setprio(1);                                          \
        _Pragma("unroll")                                                       \
        for (int fm = 0; fm < 4; ++fm)                                          \
            _Pragma("unroll")                                                   \
            for (int fn = 0; fn < 4; ++fn)                                      \
                acc[fm][fn] = __builtin_amdgcn_mfma_f32_16x16x32_bf16(          \
                    AC[1][fm], b[fn], acc[fm][fn], 0, 0, 0);                    \
        __builtin_amdgcn_s_setprio(0);                                          \
    }                                                                           \
    ADV_A();                                                                    \
} while (0)

    for (int tt = 0; tt < NT / 2; ++tt) {
        ITER(2 * tt,     aA, aB);
        ITER(2 * tt + 1, aB, aA);
    }
#undef ITER
#undef STAGE_B
#undef LOAD_A_KS
#undef ADV_A

    // epilogue: ft = bf16(acc); C/D: col=lane&15, row=(lane>>4)*4+j
    const int col16 = lane & 15, rquad = lane >> 4;
#pragma unroll
    for (int fm = 0; fm < 4; ++fm)
#pragma unroll
        for (int fn = 0; fn < 4; ++fn)
#pragma unroll
            for (int j = 0; j < 4; ++j) {
                const int m = m0 + wm * 64 + fm * 16 + rquad * 4 + j;
                const int n = n0 + wn * 64 + fn * 16 + col16;
                ftout[(size_t)m * NCOLS + n] = f2bf(acc[fm][fn][j]);
            }
}

// ---------------------------------------------------------------------------
// Kernel 4: out = LayerNorm(dec + ft/sqrt(2048)) over d=1024 per (m,b) row.
// ---------------------------------------------------------------------------
__global__ __launch_bounds__(256) void layernorm_rows(
    const unsigned short* __restrict__ ft, const float* __restrict__ dec,
    const float* __restrict__ gamma, const float* __restrict__ beta,
    float* __restrict__ out)
{
    __shared__ float ps[4], pq[4];
    const int row = blockIdx.x;
    const int tid = threadIdx.x;
    const float inv = 0.022097086912079612f;  // 1/sqrt(2048)
    const size_t base = (size_t)row * DMODEL + tid * 4;
    ushort4 u = *reinterpret_cast<const ushort4*>(ft + base);
    float4 dv = *reinterpret_cast<const float4*>(dec + base);
    float vx = dv.x + bf2f(u.x) * inv;
    float vy = dv.y + bf2f(u.y) * inv;
    float vz = dv.z + bf2f(u.z) * inv;
    float vw = dv.w + bf2f(u.w) * inv;
    float s  = vx + vy + vz + vw;
    float sq = vx * vx + vy * vy + vz * vz + vw * vw;
    for (int off = 32; off > 0; off >>= 1) {
        s  += __shfl_down(s, off);
        sq += __shfl_down(sq, off);
    }
    const int wave = tid >> 6, lane = tid & 63;
    if (lane == 0) { ps[wave] = s; pq[wave] = sq; }
    __syncthreads();
    if (tid == 0) {
        float ts = ps[0] + ps[1] + ps[2] + ps[3];
        float tq = pq[0] + pq[1] + pq[2] + pq[3];
        float mu = ts * (1.0f / DMODEL);
        float var = tq * (1.0f / DMODEL) - mu * mu;
        ps[0] = mu;
        pq[0] = rsqrtf(var + 1e-5f);
    }
    __syncthreads();
    const float mu = ps[0], rs = pq[0];
    float4 g  = *reinterpret_cast<const float4*>(gamma + tid * 4);
    float4 be = *reinterpret_cast<const float4*>(beta + tid * 4);
    float4 o;
    o.x = g.x * (vx - mu) * rs + be.x;
    o.y = g.y * (vy - mu) * rs + be.y;
    o.z = g.z * (vz - mu) * rs + be.z;
    o.w = g.w * (vw - mu) * rs + be.w;
    *reinterpret_cast<float4*>(out + base) = o;
}

extern "C" void kernel_launch(void* const* d_in, const int* in_sizes, int n_in,
                              void* d_out, int out_size, void* d_ws, size_t ws_size,
                              hipStream_t stream)
{
    const float* dec   = (const float*)d_in[0];
    const float* pos   = (const float*)d_in[1];
    const float* mems  = (const float*)d_in[2];
    const float* gamma = (const float*)d_in[3];
    const float* beta  = (const float*)d_in[4];
    const int*   addp  = (const int*)d_in[5];
    float* out = (float*)d_out;

    // ws: catT bf16 [8192][2048] (32MB) | W bf16 [1024][2048] (4MB) | ft bf16 (16MB)
    unsigned short* catT = (unsigned short*)d_ws;
    unsigned short* Wmat = catT + (size_t)NCOLS * KLEN;
    unsigned short* ft   = Wmat + (size_t)QLEN * KLEN;

    prep_transpose2<<<dim3(32, 16, 8), 256, 0, stream>>>(dec, pos, mems, addp, catT);
    fill_w<<<2048, 256, 0, stream>>>(Wmat);
    gemm_band8<<<256, 512, 0, stream>>>(Wmat, catT, ft);
    layernorm_rows<<<8192, 256, 0, stream>>>(ft, dec, gamma, beta, out);
}

// Round 10
// 61.301 us; speedup vs baseline: 1.8011x; 1.4244x over previous
//
#include <hip/hip_runtime.h>
#include <hip/hip_bf16.h>

#define QLEN   1024
#define MLEN   1024
#define KLEN   2048
#define BATCH  8
#define DMODEL 1024
#define NCOLS  (BATCH * DMODEL)   // 8192
#define FTLEN  1025

#define BM 128
#define BN 256
#define BK 64
#define NT 18   // band: K in [m0, m0+1152), 18 tiles of 64

typedef __attribute__((ext_vector_type(4))) float f32x4;
typedef __attribute__((ext_vector_type(8))) short bf16x8;

typedef __attribute__((address_space(1))) const unsigned int as1_u32;
typedef __attribute__((address_space(3))) unsigned int as3_u32;

static __device__ __forceinline__ unsigned short f2bf(float f) {
    unsigned int u = __builtin_bit_cast(unsigned int, f);
    return (unsigned short)((u + 0x7fffu + ((u >> 16) & 1u)) >> 16);
}
static __device__ __forceinline__ float bf2f(unsigned short s) {
    return __builtin_bit_cast(float, (unsigned int)s << 16);
}
static __device__ __forceinline__ unsigned int packbf(float lo, float hi) {
    return (unsigned int)f2bf(lo) | ((unsigned int)f2bf(hi) << 16);
}

// ---------------------------------------------------------------------------
// Kernel 1: z<8  : cat = concat(mems, dec) (+ pos_emb), bf16, TRANSPOSED ->
//                  catT[n][k] (pair-packed u32 LDS transpose).
//           z==8 : fill W[m][k] = cos band matrix (fused to save a launch).
// ---------------------------------------------------------------------------
__global__ __launch_bounds__(256) void prep_fused(
    const float* __restrict__ dec, const float* __restrict__ pos,
    const float* __restrict__ mems, const int* __restrict__ addp,
    unsigned short* __restrict__ catT, unsigned short* __restrict__ W)
{
    const int tid = threadIdx.x;
    if (blockIdx.z == 8) {
        // ---- fill_w: 512 blocks here, each does 4 of the 2048 orig blocks ----
        const int bchunk = (blockIdx.y * 32 + blockIdx.x) * 4;
#pragma unroll
        for (int r = 0; r < 4; ++r) {
            const int idx = (bchunk + r) * 256 + tid;
            const int m = idx >> 9;
            const int k4 = (idx & 511) * 4;
            union { unsigned short s[4]; int2 v; } u;
#pragma unroll
            for (int j = 0; j < 4; ++j) {
                const int k = k4 + j;
                const int t = k - m;
                float w = 0.0f;
                if (t >= 0 && t < FTLEN) {
                    const int rr = (m * t) % FTLEN;
                    const float x = (float)rr * (1.0f / (float)FTLEN);  // revolutions
                    float c;
                    asm("v_cos_f32 %0, %1" : "=v"(c) : "v"(x));
                    w = c * 0.03123475237772121f;   // 1/sqrt(1025)
                }
                u.s[j] = f2bf(w);
            }
            *reinterpret_cast<int2*>(&W[(size_t)m * KLEN + k4]) = u.v;
        }
        return;
    }

    __shared__ unsigned int T2[32 * 68];   // 8704 B, stride 68 u32
    const int lt = blockIdx.x, dt = blockIdx.y, b = blockIdx.z;
    const int l0 = lt * 64, d0 = dt * 64;
    const int add_position = addp[0];

    const int dloc  = (tid & 15) * 4;   // 0..60
    const int lhalf = tid >> 4;         // 0..15

    float4 vc[2][2];
#pragma unroll
    for (int p = 0; p < 2; ++p)
#pragma unroll
        for (int jl = 0; jl < 2; ++jl) {
            const int l = l0 + p * 32 + lhalf * 2 + jl;
            const float* src = (l < MLEN)
                ? (mems + (size_t)l * NCOLS + b * DMODEL + d0 + dloc)
                : (dec + (size_t)(l - MLEN) * NCOLS + b * DMODEL + d0 + dloc);
            vc[p][jl] = *reinterpret_cast<const float4*>(src);
        }
    if (add_position) {
#pragma unroll
        for (int p = 0; p < 2; ++p)
#pragma unroll
            for (int jl = 0; jl < 2; ++jl) {
                const int l = l0 + p * 32 + lhalf * 2 + jl;
                float4 pv = *reinterpret_cast<const float4*>(
                    pos + (size_t)l * DMODEL + d0 + dloc);
                vc[p][jl].x += pv.x; vc[p][jl].y += pv.y;
                vc[p][jl].z += pv.z; vc[p][jl].w += pv.w;
            }
    }
#pragma unroll
    for (int p = 0; p < 2; ++p) {
        const int lp = p * 16 + lhalf;   // 0..31
        uint4 w;
        w.x = packbf(vc[p][0].x, vc[p][1].x);
        w.y = packbf(vc[p][0].y, vc[p][1].y);
        w.z = packbf(vc[p][0].z, vc[p][1].z);
        w.w = packbf(vc[p][0].w, vc[p][1].w);
        *reinterpret_cast<uint4*>(&T2[lp * 68 + dloc]) = w;
    }
    __syncthreads();
    const int d = tid >> 2;              // 0..63
    const size_t n = (size_t)b * DMODEL + d0 + d;
#pragma unroll
    for (int q = 0; q < 2; ++q) {
        const int c8 = (tid & 3) + 4 * q;    // 0..7
        uint4 o;
        o.x = T2[(c8 * 4 + 0) * 68 + d];
        o.y = T2[(c8 * 4 + 1) * 68 + d];
        o.z = T2[(c8 * 4 + 2) * 68 + d];
        o.w = T2[(c8 * 4 + 3) * 68 + d];
        *reinterpret_cast<uint4*>(&catT[n * KLEN + l0 + c8 * 8]) = o;
    }
}

// ---------------------------------------------------------------------------
// Kernel 2: banded GEMM v9 — band4 stripped to the minimal 2-phase sync:
// per K-tile exactly { vmcnt(6); s_barrier; ph0: 8 ds_read | 3 stage | 16 MFMA;
// ph1: same }. ONE barrier + ONE vmcnt per tile; lgkm waits left to the
// compiler's fine-grained scheduling (m97 evidence). Triple-buffered LDS,
// T2 both-sides XOR swizzle, counted vmcnt (2 tiles in flight), setprio.
// WAR safety: each wave's ds_reads of buf[t] are complete (MFMA data dep)
// before it reaches tile t+1's top barrier, which precedes any STAGE into
// buf[(t+3)%3] == buf[t].
// ---------------------------------------------------------------------------
__global__ __launch_bounds__(512) void gemm_band9(
    const unsigned short* __restrict__ W,     // [1024][2048]
    const unsigned short* __restrict__ catT,  // [8192][2048]
    unsigned short* __restrict__ ftout)       // bf16 [1024][8192]
{
    __shared__ unsigned short Alds[3][BM * BK];   // 3 x 16KB
    __shared__ unsigned short Blds[3][BN * BK];   // 3 x 32KB  (total 144KB)

    const int tid = threadIdx.x;
    const int wave = tid >> 6, lane = tid & 63;

    const int bid = blockIdx.x;
    const int xcd = bid & 7;
    const int kk = bid >> 3;              // 0..31
    const int m_idx = kk >> 2;            // 0..7
    const int n_idx = xcd * 4 + (kk & 3); // 0..31
    const int m0 = m_idx * BM, n0 = n_idx * BN;
    const int wm = wave >> 2, wn = wave & 3;   // 2 x 4 wave grid

    f32x4 acc[4][4];
    for (int i = 0; i < 4; ++i)
        for (int j = 0; j < 4; ++j)
            acc[i][j] = (f32x4){0.f, 0.f, 0.f, 0.f};

    const int srow = tid >> 3;           // 0..63
    const int scol = (((tid & 7) ^ ((tid >> 3) & 7)) * 8);  // pre-swizzled src col
    const int fr = lane & 15;
    const int kg = lane >> 4;
    const int rswz = (fr & 7) * 8;       // read-side XOR (elements)

#define STAGE_LOAD_A(S, T, P) do {                                              \
    const int k0_ = m0 + (T) * BK;                                              \
    const int row = (P) * 64 + srow;                                            \
    __builtin_amdgcn_global_load_lds(                                           \
        (as1_u32*)(const void*)(W + (size_t)(m0 + row) * KLEN + k0_ + scol),    \
        (as3_u32*)(void*)(&Alds[S][row * BK + scol]), 16, 0, 0);                \
} while (0)
#define STAGE_LOAD_B(S, T, P) do {                                              \
    const int k0_ = m0 + (T) * BK;                                              \
    const int row = (P) * 64 + srow;                                            \
    __builtin_amdgcn_global_load_lds(                                           \
        (as1_u32*)(const void*)(catT + (size_t)(n0 + row) * KLEN + k0_ + scol), \
        (as3_u32*)(void*)(&Blds[S][row * BK + scol]), 16, 0, 0);                \
} while (0)
#define STAGE_ALL(S, T) do {                                                    \
    STAGE_LOAD_A(S, T, 0); STAGE_LOAD_A(S, T, 1);                               \
    STAGE_LOAD_B(S, T, 0); STAGE_LOAD_B(S, T, 1);                               \
    STAGE_LOAD_B(S, T, 2); STAGE_LOAD_B(S, T, 3);                               \
} while (0)

    STAGE_ALL(0, 0);
    STAGE_ALL(1, 1);

    for (int t = 0; t < NT; ++t) {
        // retire tile t's 6 loads; keep tile t+1's in flight
        if (t == NT - 1)
            asm volatile("s_waitcnt vmcnt(0)" ::: "memory");
        else
            asm volatile("s_waitcnt vmcnt(6)" ::: "memory");
        __builtin_amdgcn_s_barrier();

        const unsigned short* Ab = Alds[t % 3];
        const unsigned short* Bb = Blds[t % 3];
        const int s2 = (t + 2) % 3;
        const bool pf = (t + 2 < NT);

        // ---------------- phase 0 (ks = 0) ----------------
        {
            bf16x8 a[4], b[4];
#pragma unroll
            for (int f = 0; f < 4; ++f)
                a[f] = *reinterpret_cast<const bf16x8*>(
                    Ab + (wm * 64 + f * 16 + fr) * BK + ((kg * 8) ^ rswz));
#pragma unroll
            for (int f = 0; f < 4; ++f)
                b[f] = *reinterpret_cast<const bf16x8*>(
                    Bb + (wn * 64 + f * 16 + fr) * BK + ((kg * 8) ^ rswz));
            if (pf) { STAGE_LOAD_A(s2, t + 2, 0); STAGE_LOAD_B(s2, t + 2, 0); STAGE_LOAD_B(s2, t + 2, 1); }
            __builtin_amdgcn_s_setprio(1);
#pragma unroll
            for (int fm = 0; fm < 4; ++fm)
#pragma unroll
                for (int fn = 0; fn < 4; ++fn)
                    acc[fm][fn] = __builtin_amdgcn_mfma_f32_16x16x32_bf16(
                        a[fm], b[fn], acc[fm][fn], 0, 0, 0);
            __builtin_amdgcn_s_setprio(0);
        }
        // ---------------- phase 1 (ks = 1) ----------------
        {
            bf16x8 a[4], b[4];
#pragma unroll
            for (int f = 0; f < 4; ++f)
                a[f] = *reinterpret_cast<const bf16x8*>(
                    Ab + (wm * 64 + f * 16 + fr) * BK + ((32 + kg * 8) ^ rswz));
#pragma unroll
            for (int f = 0; f < 4; ++f)
                b[f] = *reinterpret_cast<const bf16x8*>(
                    Bb + (wn * 64 + f * 16 + fr) * BK + ((32 + kg * 8) ^ rswz));
            if (pf) { STAGE_LOAD_A(s2, t + 2, 1); STAGE_LOAD_B(s2, t + 2, 2); STAGE_LOAD_B(s2, t + 2, 3); }
            __builtin_amdgcn_s_setprio(1);
#pragma unroll
            for (int fm = 0; fm < 4; ++fm)
#pragma unroll
                for (int fn = 0; fn < 4; ++fn)
                    acc[fm][fn] = __builtin_amdgcn_mfma_f32_16x16x32_bf16(
                        a[fm], b[fn], acc[fm][fn], 0, 0, 0);
            __builtin_amdgcn_s_setprio(0);
        }
    }
#undef STAGE_ALL
#undef STAGE_LOAD_A
#undef STAGE_LOAD_B

    // epilogue: ft = bf16(acc); C/D: col=lane&15, row=(lane>>4)*4+j
    const int col16 = lane & 15, rquad = lane >> 4;
#pragma unroll
    for (int fm = 0; fm < 4; ++fm)
#pragma unroll
        for (int fn = 0; fn < 4; ++fn)
#pragma unroll
            for (int j = 0; j < 4; ++j) {
                const int m = m0 + wm * 64 + fm * 16 + rquad * 4 + j;
                const int n = n0 + wn * 64 + fn * 16 + col16;
                ftout[(size_t)m * NCOLS + n] = f2bf(acc[fm][fn][j]);
            }
}

// ---------------------------------------------------------------------------
// Kernel 3: out = LayerNorm(dec + ft/sqrt(2048)) over d=1024 per (m,b) row.
// ---------------------------------------------------------------------------
__global__ __launch_bounds__(256) void layernorm_rows(
    const unsigned short* __restrict__ ft, const float* __restrict__ dec,
    const float* __restrict__ gamma, const float* __restrict__ beta,
    float* __restrict__ out)
{
    __shared__ float ps[4], pq[4];
    const int row = blockIdx.x;
    const int tid = threadIdx.x;
    const float inv = 0.022097086912079612f;  // 1/sqrt(2048)
    const size_t base = (size_t)row * DMODEL + tid * 4;
    ushort4 u = *reinterpret_cast<const ushort4*>(ft + base);
    float4 dv = *reinterpret_cast<const float4*>(dec + base);
    float vx = dv.x + bf2f(u.x) * inv;
    float vy = dv.y + bf2f(u.y) * inv;
    float vz = dv.z + bf2f(u.z) * inv;
    float vw = dv.w + bf2f(u.w) * inv;
    float s  = vx + vy + vz + vw;
    float sq = vx * vx + vy * vy + vz * vz + vw * vw;
    for (int off = 32; off > 0; off >>= 1) {
        s  += __shfl_down(s, off);
        sq += __shfl_down(sq, off);
    }
    const int wave = tid >> 6, lane = tid & 63;
    if (lane == 0) { ps[wave] = s; pq[wave] = sq; }
    __syncthreads();
    if (tid == 0) {
        float ts = ps[0] + ps[1] + ps[2] + ps[3];
        float tq = pq[0] + pq[1] + pq[2] + pq[3];
        float mu = ts * (1.0f / DMODEL);
        float var = tq * (1.0f / DMODEL) - mu * mu;
        ps[0] = mu;
        pq[0] = rsqrtf(var + 1e-5f);
    }
    __syncthreads();
    const float mu = ps[0], rs = pq[0];
    float4 g  = *reinterpret_cast<const float4*>(gamma + tid * 4);
    float4 be = *reinterpret_cast<const float4*>(beta + tid * 4);
    float4 o;
    o.x = g.x * (vx - mu) * rs + be.x;
    o.y = g.y * (vy - mu) * rs + be.y;
    o.z = g.z * (vz - mu) * rs + be.z;
    o.w = g.w * (vw - mu) * rs + be.w;
    *reinterpret_cast<float4*>(out + base) = o;
}

extern "C" void kernel_launch(void* const* d_in, const int* in_sizes, int n_in,
                              void* d_out, int out_size, void* d_ws, size_t ws_size,
                              hipStream_t stream)
{
    const float* dec   = (const float*)d_in[0];
    const float* pos   = (const float*)d_in[1];
    const float* mems  = (const float*)d_in[2];
    const float* gamma = (const float*)d_in[3];
    const float* beta  = (const float*)d_in[4];
    const int*   addp  = (const int*)d_in[5];
    float* out = (float*)d_out;

    // ws: catT bf16 [8192][2048] (32MB) | W bf16 [1024][2048] (4MB) | ft bf16 (16MB)
    unsigned short* catT = (unsigned short*)d_ws;
    unsigned short* Wmat = catT + (size_t)NCOLS * KLEN;
    unsigned short* ft   = Wmat + (size_t)QLEN * KLEN;

    prep_fused<<<dim3(32, 16, 9), 256, 0, stream>>>(dec, pos, mems, addp, catT, Wmat);
    gemm_band9<<<256, 512, 0, stream>>>(Wmat, catT, ft);
    layernorm_rows<<<8192, 256, 0, stream>>>(ft, dec, gamma, beta, out);
}

// Round 11
// 59.909 us; speedup vs baseline: 1.8429x; 1.0232x over previous
//
#include <hip/hip_runtime.h>
#include <hip/hip_bf16.h>

#define QLEN   1024
#define MLEN   1024
#define KLEN   2048
#define BATCH  8
#define DMODEL 1024
#define NCOLS  (BATCH * DMODEL)   // 8192
#define FTLEN  1025

#define BM 128
#define BN 256
#define BK 64
#define NT 18   // band: K in [m0, m0+1152), 18 tiles of 64

typedef __attribute__((ext_vector_type(4))) float f32x4;
typedef __attribute__((ext_vector_type(8))) short bf16x8;

typedef __attribute__((address_space(1))) const unsigned int as1_u32;
typedef __attribute__((address_space(3))) unsigned int as3_u32;

static __device__ __forceinline__ unsigned short f2bf(float f) {
    unsigned int u = __builtin_bit_cast(unsigned int, f);
    return (unsigned short)((u + 0x7fffu + ((u >> 16) & 1u)) >> 16);
}
static __device__ __forceinline__ float bf2f(unsigned short s) {
    return __builtin_bit_cast(float, (unsigned int)s << 16);
}
static __device__ __forceinline__ unsigned int packbf(float lo, float hi) {
    return (unsigned int)f2bf(lo) | ((unsigned int)f2bf(hi) << 16);
}

// ---------------------------------------------------------------------------
// Kernel 1: z<8  : cat = concat(mems, dec) (+ pos_emb), bf16, TRANSPOSED ->
//                  catT[n][k] (pair-packed u32 LDS transpose).
//           z==8 : fill W[m][k] = cos band matrix (fused to save a launch).
// ---------------------------------------------------------------------------
__global__ __launch_bounds__(256) void prep_fused(
    const float* __restrict__ dec, const float* __restrict__ pos,
    const float* __restrict__ mems, const int* __restrict__ addp,
    unsigned short* __restrict__ catT, unsigned short* __restrict__ W)
{
    const int tid = threadIdx.x;
    if (blockIdx.z == 8) {
        const int bchunk = (blockIdx.y * 32 + blockIdx.x) * 4;
#pragma unroll
        for (int r = 0; r < 4; ++r) {
            const int idx = (bchunk + r) * 256 + tid;
            const int m = idx >> 9;
            const int k4 = (idx & 511) * 4;
            union { unsigned short s[4]; int2 v; } u;
#pragma unroll
            for (int j = 0; j < 4; ++j) {
                const int k = k4 + j;
                const int t = k - m;
                float w = 0.0f;
                if (t >= 0 && t < FTLEN) {
                    const int rr = (m * t) % FTLEN;
                    const float x = (float)rr * (1.0f / (float)FTLEN);  // revolutions
                    float c;
                    asm("v_cos_f32 %0, %1" : "=v"(c) : "v"(x));
                    w = c * 0.03123475237772121f;   // 1/sqrt(1025)
                }
                u.s[j] = f2bf(w);
            }
            *reinterpret_cast<int2*>(&W[(size_t)m * KLEN + k4]) = u.v;
        }
        return;
    }

    __shared__ unsigned int T2[32 * 68];   // 8704 B, stride 68 u32
    const int lt = blockIdx.x, dt = blockIdx.y, b = blockIdx.z;
    const int l0 = lt * 64, d0 = dt * 64;
    const int add_position = addp[0];

    const int dloc  = (tid & 15) * 4;   // 0..60
    const int lhalf = tid >> 4;         // 0..15

    float4 vc[2][2];
#pragma unroll
    for (int p = 0; p < 2; ++p)
#pragma unroll
        for (int jl = 0; jl < 2; ++jl) {
            const int l = l0 + p * 32 + lhalf * 2 + jl;
            const float* src = (l < MLEN)
                ? (mems + (size_t)l * NCOLS + b * DMODEL + d0 + dloc)
                : (dec + (size_t)(l - MLEN) * NCOLS + b * DMODEL + d0 + dloc);
            vc[p][jl] = *reinterpret_cast<const float4*>(src);
        }
    if (add_position) {
#pragma unroll
        for (int p = 0; p < 2; ++p)
#pragma unroll
            for (int jl = 0; jl < 2; ++jl) {
                const int l = l0 + p * 32 + lhalf * 2 + jl;
                float4 pv = *reinterpret_cast<const float4*>(
                    pos + (size_t)l * DMODEL + d0 + dloc);
                vc[p][jl].x += pv.x; vc[p][jl].y += pv.y;
                vc[p][jl].z += pv.z; vc[p][jl].w += pv.w;
            }
    }
#pragma unroll
    for (int p = 0; p < 2; ++p) {
        const int lp = p * 16 + lhalf;   // 0..31
        uint4 w;
        w.x = packbf(vc[p][0].x, vc[p][1].x);
        w.y = packbf(vc[p][0].y, vc[p][1].y);
        w.z = packbf(vc[p][0].z, vc[p][1].z);
        w.w = packbf(vc[p][0].w, vc[p][1].w);
        *reinterpret_cast<uint4*>(&T2[lp * 68 + dloc]) = w;
    }
    __syncthreads();
    const int d = tid >> 2;              // 0..63
    const size_t n = (size_t)b * DMODEL + d0 + d;
#pragma unroll
    for (int q = 0; q < 2; ++q) {
        const int c8 = (tid & 3) + 4 * q;    // 0..7
        uint4 o;
        o.x = T2[(c8 * 4 + 0) * 68 + d];
        o.y = T2[(c8 * 4 + 1) * 68 + d];
        o.z = T2[(c8 * 4 + 2) * 68 + d];
        o.w = T2[(c8 * 4 + 3) * 68 + d];
        *reinterpret_cast<uint4*>(&catT[n * KLEN + l0 + c8 * 8]) = o;
    }
}

// ---------------------------------------------------------------------------
// Kernel 2: banded GEMM v10 — identical minimal-sync loop to v9 (one barrier
// + one counted vmcnt per K-tile, compiler-interleaved tile body); epilogue
// now fuses the residual: x[m][n] = bf16(dec[m][n] + acc*inv). dec is
// L3-resident (prep just read it), read in the latency-tolerant epilogue.
// ---------------------------------------------------------------------------
__global__ __launch_bounds__(512) void gemm_band10(
    const unsigned short* __restrict__ W,     // [1024][2048]
    const unsigned short* __restrict__ catT,  // [8192][2048]
    const float* __restrict__ dec,            // [1024][8192]
    unsigned short* __restrict__ xout)        // bf16 [1024][8192]
{
    __shared__ unsigned short Alds[3][BM * BK];   // 3 x 16KB
    __shared__ unsigned short Blds[3][BN * BK];   // 3 x 32KB  (total 144KB)

    const int tid = threadIdx.x;
    const int wave = tid >> 6, lane = tid & 63;

    const int bid = blockIdx.x;
    const int xcd = bid & 7;
    const int kk = bid >> 3;              // 0..31
    const int m_idx = kk >> 2;            // 0..7
    const int n_idx = xcd * 4 + (kk & 3); // 0..31
    const int m0 = m_idx * BM, n0 = n_idx * BN;
    const int wm = wave >> 2, wn = wave & 3;   // 2 x 4 wave grid

    f32x4 acc[4][4];
    for (int i = 0; i < 4; ++i)
        for (int j = 0; j < 4; ++j)
            acc[i][j] = (f32x4){0.f, 0.f, 0.f, 0.f};

    const int srow = tid >> 3;           // 0..63
    const int scol = (((tid & 7) ^ ((tid >> 3) & 7)) * 8);  // pre-swizzled src col
    const int fr = lane & 15;
    const int kg = lane >> 4;
    const int rswz = (fr & 7) * 8;       // read-side XOR (elements)

#define STAGE_LOAD_A(S, T, P) do {                                              \
    const int k0_ = m0 + (T) * BK;                                              \
    const int row = (P) * 64 + srow;                                            \
    __builtin_amdgcn_global_load_lds(                                           \
        (as1_u32*)(const void*)(W + (size_t)(m0 + row) * KLEN + k0_ + scol),    \
        (as3_u32*)(void*)(&Alds[S][row * BK + scol]), 16, 0, 0);                \
} while (0)
#define STAGE_LOAD_B(S, T, P) do {                                              \
    const int k0_ = m0 + (T) * BK;                                              \
    const int row = (P) * 64 + srow;                                            \
    __builtin_amdgcn_global_load_lds(                                           \
        (as1_u32*)(const void*)(catT + (size_t)(n0 + row) * KLEN + k0_ + scol), \
        (as3_u32*)(void*)(&Blds[S][row * BK + scol]), 16, 0, 0);                \
} while (0)
#define STAGE_ALL(S, T) do {                                                    \
    STAGE_LOAD_A(S, T, 0); STAGE_LOAD_A(S, T, 1);                               \
    STAGE_LOAD_B(S, T, 0); STAGE_LOAD_B(S, T, 1);                               \
    STAGE_LOAD_B(S, T, 2); STAGE_LOAD_B(S, T, 3);                               \
} while (0)

    STAGE_ALL(0, 0);
    STAGE_ALL(1, 1);

    for (int t = 0; t < NT; ++t) {
        if (t == NT - 1)
            asm volatile("s_waitcnt vmcnt(0)" ::: "memory");
        else
            asm volatile("s_waitcnt vmcnt(6)" ::: "memory");
        __builtin_amdgcn_s_barrier();

        const unsigned short* Ab = Alds[t % 3];
        const unsigned short* Bb = Blds[t % 3];
        const int s2 = (t + 2) % 3;
        const bool pf = (t + 2 < NT);

        // ---------------- phase 0 (ks = 0) ----------------
        {
            bf16x8 a[4], b[4];
#pragma unroll
            for (int f = 0; f < 4; ++f)
                a[f] = *reinterpret_cast<const bf16x8*>(
                    Ab + (wm * 64 + f * 16 + fr) * BK + ((kg * 8) ^ rswz));
#pragma unroll
            for (int f = 0; f < 4; ++f)
                b[f] = *reinterpret_cast<const bf16x8*>(
                    Bb + (wn * 64 + f * 16 + fr) * BK + ((kg * 8) ^ rswz));
            if (pf) { STAGE_LOAD_A(s2, t + 2, 0); STAGE_LOAD_B(s2, t + 2, 0); STAGE_LOAD_B(s2, t + 2, 1); }
            __builtin_amdgcn_s_setprio(1);
#pragma unroll
            for (int fm = 0; fm < 4; ++fm)
#pragma unroll
                for (int fn = 0; fn < 4; ++fn)
                    acc[fm][fn] = __builtin_amdgcn_mfma_f32_16x16x32_bf16(
                        a[fm], b[fn], acc[fm][fn], 0, 0, 0);
            __builtin_amdgcn_s_setprio(0);
        }
        // ---------------- phase 1 (ks = 1) ----------------
        {
            bf16x8 a[4], b[4];
#pragma unroll
            for (int f = 0; f < 4; ++f)
                a[f] = *reinterpret_cast<const bf16x8*>(
                    Ab + (wm * 64 + f * 16 + fr) * BK + ((32 + kg * 8) ^ rswz));
#pragma unroll
            for (int f = 0; f < 4; ++f)
                b[f] = *reinterpret_cast<const bf16x8*>(
                    Bb + (wn * 64 + f * 16 + fr) * BK + ((32 + kg * 8) ^ rswz));
            if (pf) { STAGE_LOAD_A(s2, t + 2, 1); STAGE_LOAD_B(s2, t + 2, 2); STAGE_LOAD_B(s2, t + 2, 3); }
            __builtin_amdgcn_s_setprio(1);
#pragma unroll
            for (int fm = 0; fm < 4; ++fm)
#pragma unroll
                for (int fn = 0; fn < 4; ++fn)
                    acc[fm][fn] = __builtin_amdgcn_mfma_f32_16x16x32_bf16(
                        a[fm], b[fn], acc[fm][fn], 0, 0, 0);
            __builtin_amdgcn_s_setprio(0);
        }
    }
#undef STAGE_ALL
#undef STAGE_LOAD_A
#undef STAGE_LOAD_B

    // epilogue: x = bf16(dec + acc/sqrt(2048)); C/D: col=lane&15, row=(lane>>4)*4+j
    const float inv = 0.022097086912079612f;  // 1/sqrt(2048)
    const int col16 = lane & 15, rquad = lane >> 4;
#pragma unroll
    for (int fm = 0; fm < 4; ++fm)
#pragma unroll
        for (int fn = 0; fn < 4; ++fn)
#pragma unroll
            for (int j = 0; j < 4; ++j) {
                const int m = m0 + wm * 64 + fm * 16 + rquad * 4 + j;
                const int n = n0 + wn * 64 + fn * 16 + col16;
                const size_t o = (size_t)m * NCOLS + n;
                xout[o] = f2bf(dec[o] + acc[fm][fn][j] * inv);
            }
}

// ---------------------------------------------------------------------------
// Kernel 3: out = LayerNorm(x) over d=1024 per (m,b) row. x bf16 (already
// includes the dec residual), out f32. Traffic 48 MB (was 80).
// ---------------------------------------------------------------------------
__global__ __launch_bounds__(256) void layernorm_rows(
    const unsigned short* __restrict__ x,
    const float* __restrict__ gamma, const float* __restrict__ beta,
    float* __restrict__ out)
{
    __shared__ float ps[4], pq[4];
    const int row = blockIdx.x;
    const int tid = threadIdx.x;
    const size_t base = (size_t)row * DMODEL + tid * 4;
    ushort4 u = *reinterpret_cast<const ushort4*>(x + base);
    float vx = bf2f(u.x), vy = bf2f(u.y), vz = bf2f(u.z), vw = bf2f(u.w);
    float s  = vx + vy + vz + vw;
    float sq = vx * vx + vy * vy + vz * vz + vw * vw;
    for (int off = 32; off > 0; off >>= 1) {
        s  += __shfl_down(s, off);
        sq += __shfl_down(sq, off);
    }
    const int wave = tid >> 6, lane = tid & 63;
    if (lane == 0) { ps[wave] = s; pq[wave] = sq; }
    __syncthreads();
    if (tid == 0) {
        float ts = ps[0] + ps[1] + ps[2] + ps[3];
        float tq = pq[0] + pq[1] + pq[2] + pq[3];
        float mu = ts * (1.0f / DMODEL);
        float var = tq * (1.0f / DMODEL) - mu * mu;
        ps[0] = mu;
        pq[0] = rsqrtf(var + 1e-5f);
    }
    __syncthreads();
    const float mu = ps[0], rs = pq[0];
    float4 g  = *reinterpret_cast<const float4*>(gamma + tid * 4);
    float4 be = *reinterpret_cast<const float4*>(beta + tid * 4);
    float4 o;
    o.x = g.x * (vx - mu) * rs + be.x;
    o.y = g.y * (vy - mu) * rs + be.y;
    o.z = g.z * (vz - mu) * rs + be.z;
    o.w = g.w * (vw - mu) * rs + be.w;
    *reinterpret_cast<float4*>(out + base) = o;
}

extern "C" void kernel_launch(void* const* d_in, const int* in_sizes, int n_in,
                              void* d_out, int out_size, void* d_ws, size_t ws_size,
                              hipStream_t stream)
{
    const float* dec   = (const float*)d_in[0];
    const float* pos   = (const float*)d_in[1];
    const float* mems  = (const float*)d_in[2];
    const float* gamma = (const float*)d_in[3];
    const float* beta  = (const float*)d_in[4];
    const int*   addp  = (const int*)d_in[5];
    float* out = (float*)d_out;

    // ws: catT bf16 [8192][2048] (32MB) | W bf16 [1024][2048] (4MB) | x bf16 (16MB)
    unsigned short* catT = (unsigned short*)d_ws;
    unsigned short* Wmat = catT + (size_t)NCOLS * KLEN;
    unsigned short* x    = Wmat + (size_t)QLEN * KLEN;

    prep_fused<<<dim3(32, 16, 9), 256, 0, stream>>>(dec, pos, mems, addp, catT, Wmat);
    gemm_band10<<<256, 512, 0, stream>>>(Wmat, catT, dec, x);
    layernorm_rows<<<8192, 256, 0, stream>>>(x, gamma, beta, out);
}